// Round 2
// baseline (582.895 us; speedup 1.0000x reference)
//
#include <hip/hip_runtime.h>

// Problem constants (from reference): D=4, J=256, K=512, H=512, B=1024
#define J_ 256
#define K_ 512
#define H_ 512
#define B_ 1024
#define BK 64

typedef float f32x4 __attribute__((ext_vector_type(4)));
typedef unsigned int u32x4 __attribute__((ext_vector_type(4)));
typedef unsigned short u16x4 __attribute__((ext_vector_type(4)));
typedef unsigned short u16x8 __attribute__((ext_vector_type(8)));
typedef __bf16 bf16x8 __attribute__((ext_vector_type(8)));

// f32 -> bf16 round-to-nearest-even (manual; inputs are finite)
__device__ __forceinline__ unsigned short f2bf(float f) {
    unsigned int u = __float_as_uint(f);
    u += 0x7fffu + ((u >> 16) & 1u);
    return (unsigned short)(u >> 16);
}

// Prep: x f32 -> bf16 into ws; init out: mu[b,j] = b1[j]; logvar tail.
// grid 512 x 256 threads = 131072 threads; 4 x-elements each.
__global__ __launch_bounds__(256) void prep_kernel(
    const float* __restrict__ x, const float* __restrict__ b1,
    const float* __restrict__ logvar, unsigned short* __restrict__ xbf,
    float* __restrict__ out) {
    int t = blockIdx.x * 256 + threadIdx.x;
    {
        f32x4 v = *(const f32x4*)(x + (size_t)t * 4);
        u16x4 o;
        o[0] = f2bf(v[0]); o[1] = f2bf(v[1]); o[2] = f2bf(v[2]); o[3] = f2bf(v[3]);
        *(u16x4*)(xbf + (size_t)t * 4) = o;
    }
    if (t < (B_ * J_) / 4) {   // 65536 threads init mu with b1 broadcast
        int b = t >> 6;          // 4 j's per thread: linear = t*4
        int j4 = (t & 63) << 2;
        f32x4 bb = *(const f32x4*)(b1 + j4);
        *(f32x4*)(out + ((size_t)b << 8) + j4) = bb;
    }
    if (t < 4) out[B_ * J_ + t] = logvar[t];
}

// Main grouped-GEMM kernel.
// Logical block (j, mb, nb): 256 x 8 x 4 = 8192 blocks, 256 threads (4 waves).
// Tile: 128(M=batch) x 128(N=h) per block, wave tile 64x64, BK=64, K=512.
// XCD swizzle: all 32 blocks of one j land on one XCD (p%8) for L2 reuse of W0[j].
__global__ __launch_bounds__(256, 2) void enc_kernel(
    const unsigned short* __restrict__ xbf,
    const float* __restrict__ W0,
    const float* __restrict__ wmask,
    const int* __restrict__ ip,
    const float* __restrict__ b0,
    const float* __restrict__ W1,
    float* __restrict__ out) {
    // 128 rows x 64 bf16 = 128B per row, 16KB each
    __shared__ unsigned char ldsA[128 * 128];
    __shared__ unsigned char ldsB[128 * 128];

    int p = blockIdx.x;
    int xcd = p & 7;
    int q = p >> 3;                 // 0..1023
    int j = (xcd << 5) + (q >> 5);  // 0..255
    int inner = q & 31;
    int m0 = (inner >> 2) << 7;     // batch-row base
    int h0 = (inner & 3) << 7;      // h-col base

    int i = ip[0];
    const float* w0j = W0 + (size_t)j * (H_ * K_);
    const float* wij = wmask + ((size_t)i * J_ + j) * K_;

    int tid = threadIdx.x;
    int lane = tid & 63;
    int wv = tid >> 6;
    int wm = wv >> 1, wn = wv & 1;  // wave grid 2(m) x 2(n)
    int lr = lane & 15, lg = lane >> 4;

    // staging coords (constant across it since 256 % 8 == 0)
    int srow0 = tid >> 3;   // +it*32
    int c = tid & 7;        // 8-element (16B) chunk within the 64-k row

    f32x4 acc[4][4] = {};

    for (int ks = 0; ks < K_ / BK; ++ks) {
        int k0 = ks * BK;
        // --- stage x tile: 128 x 64 bf16 (already converted) ---
        #pragma unroll
        for (int it = 0; it < 4; ++it) {
            int r = srow0 + it * 32;
            u32x4 v = *(const u32x4*)(xbf + (size_t)(m0 + r) * K_ + k0 + c * 8);
            *(u32x4*)(ldsA + r * 128 + ((c * 16) ^ ((r & 7) << 4))) = v;
        }
        // --- stage W0' tile: 128 x 64, f32 load * wi -> bf16 ---
        f32x4 s0 = *(const f32x4*)(wij + k0 + c * 8);
        f32x4 s1 = *(const f32x4*)(wij + k0 + c * 8 + 4);
        #pragma unroll
        for (int it = 0; it < 4; ++it) {
            int hr = srow0 + it * 32;
            const float* src = w0j + (size_t)(h0 + hr) * K_ + k0 + c * 8;
            f32x4 a0 = *(const f32x4*)(src);
            f32x4 a1 = *(const f32x4*)(src + 4);
            a0 *= s0; a1 *= s1;
            u16x8 bv;
            #pragma unroll
            for (int e = 0; e < 4; ++e) { bv[e] = f2bf(a0[e]); bv[e + 4] = f2bf(a1[e]); }
            *(u16x8*)(ldsB + hr * 128 + ((c * 16) ^ ((hr & 7) << 4))) = bv;
        }
        __syncthreads();
        // --- compute: 2 k-frags x 4 m-frags x 4 n-frags ---
        #pragma unroll
        for (int kf = 0; kf < 2; ++kf) {
            bf16x8 af[4], bfr[4];
            #pragma unroll
            for (int mf = 0; mf < 4; ++mf) {
                int r = (wm << 6) + (mf << 4) + lr;
                af[mf] = *(const bf16x8*)(ldsA + r * 128 +
                          (((kf << 6) + (lg << 4)) ^ ((r & 7) << 4)));
            }
            #pragma unroll
            for (int nf = 0; nf < 4; ++nf) {
                int hrw = (wn << 6) + (nf << 4) + lr;
                bfr[nf] = *(const bf16x8*)(ldsB + hrw * 128 +
                          (((kf << 6) + (lg << 4)) ^ ((hrw & 7) << 4)));
            }
            #pragma unroll
            for (int mf = 0; mf < 4; ++mf)
                #pragma unroll
                for (int nf = 0; nf < 4; ++nf)
                    acc[mf][nf] = __builtin_amdgcn_mfma_f32_16x16x32_bf16(
                        af[mf], bfr[nf], acc[mf][nf], 0, 0, 0);
        }
        __syncthreads();
    }

    // --- fused epilogue: h = leaky(acc + b0); partial mu = h . W1 ---
    float b0v[4], w1v[4];
    #pragma unroll
    for (int nf = 0; nf < 4; ++nf) {
        int h = h0 + (wn << 6) + (nf << 4) + lr;
        b0v[nf] = b0[(size_t)j * H_ + h];
        w1v[nf] = W1[(size_t)j * H_ + h];
    }
    #pragma unroll
    for (int mf = 0; mf < 4; ++mf) {
        #pragma unroll
        for (int rg = 0; rg < 4; ++rg) {
            float ps = 0.f;
            #pragma unroll
            for (int nf = 0; nf < 4; ++nf) {
                float hv = acc[mf][nf][rg] + b0v[nf];   // C/D: col=lane&15, row=lg*4+rg
                hv = hv > 0.f ? hv : 0.01f * hv;
                ps += hv * w1v[nf];
            }
            // reduce across the 16 cols held by lanes sharing lg
            ps += __shfl_xor(ps, 1);
            ps += __shfl_xor(ps, 2);
            ps += __shfl_xor(ps, 4);
            ps += __shfl_xor(ps, 8);
            if (lr == 0) {
                int row = m0 + (wm << 6) + (mf << 4) + (lg << 2) + rg;
                atomicAdd(out + (size_t)row * J_ + j, ps);
            }
        }
    }
}

extern "C" void kernel_launch(void* const* d_in, const int* in_sizes, int n_in,
                              void* d_out, int out_size, void* d_ws, size_t ws_size,
                              hipStream_t stream) {
    const float* x      = (const float*)d_in[0];
    const int*   ip     = (const int*)d_in[1];
    const float* wmask  = (const float*)d_in[2];
    const float* W0     = (const float*)d_in[3];
    const float* b0     = (const float*)d_in[4];
    const float* W1     = (const float*)d_in[5];
    const float* b1     = (const float*)d_in[6];
    const float* logvar = (const float*)d_in[7];
    float* out = (float*)d_out;
    unsigned short* xbf = (unsigned short*)d_ws;  // 1024*512 bf16 = 1 MB

    prep_kernel<<<512, 256, 0, stream>>>(x, b1, logvar, xbf, out);
    enc_kernel<<<8192, 256, 0, stream>>>(xbf, W0, wmask, ip, b0, W1, out);
}

// Round 3
// 582.433 us; speedup vs baseline: 1.0008x; 1.0008x over previous
//
#include <hip/hip_runtime.h>

// Problem constants (from reference): D=4, J=256, K=512, H=512, B=1024
#define J_ 256
#define K_ 512
#define H_ 512
#define B_ 1024
#define BK 64

typedef float f32x4 __attribute__((ext_vector_type(4)));
typedef unsigned int u32x4 __attribute__((ext_vector_type(4)));
typedef unsigned short u16x4 __attribute__((ext_vector_type(4)));
typedef unsigned short u16x8 __attribute__((ext_vector_type(8)));
typedef __bf16 bf16x8 __attribute__((ext_vector_type(8)));

// f32 -> bf16 round-to-nearest-even (manual; inputs are finite)
__device__ __forceinline__ unsigned short f2bf(float f) {
    unsigned int u = __float_as_uint(f);
    u += 0x7fffu + ((u >> 16) & 1u);
    return (unsigned short)(u >> 16);
}

// async global->LDS, 16B per lane; dest must be wave-uniform base (HW adds lane*16)
__device__ __forceinline__ void gload_lds16(const void* g, void* l) {
    __builtin_amdgcn_global_load_lds(
        (const __attribute__((address_space(1))) unsigned int*)g,
        (__attribute__((address_space(3))) unsigned int*)l, 16, 0, 0);
}

// Prep: x f32 -> bf16 into ws; init out: mu[b,j] = b1[j]; logvar tail.
__global__ __launch_bounds__(256) void prep_kernel(
    const float* __restrict__ x, const float* __restrict__ b1,
    const float* __restrict__ logvar, unsigned short* __restrict__ xbf,
    float* __restrict__ out) {
    int t = blockIdx.x * 256 + threadIdx.x;
    {
        f32x4 v = *(const f32x4*)(x + (size_t)t * 4);
        u16x4 o;
        o[0] = f2bf(v[0]); o[1] = f2bf(v[1]); o[2] = f2bf(v[2]); o[3] = f2bf(v[3]);
        *(u16x4*)(xbf + (size_t)t * 4) = o;
    }
    if (t < (B_ * J_) / 4) {
        int b = t >> 6;
        int j4 = (t & 63) << 2;
        f32x4 bb = *(const f32x4*)(b1 + j4);
        *(f32x4*)(out + ((size_t)b << 8) + j4) = bb;
    }
    if (t < 4) out[B_ * J_ + t] = logvar[t];
}

// W0' = bf16(W0 * wi), memory-bound pass. 8 elems/thread, 32768 blocks x 256.
__global__ __launch_bounds__(256) void wprep_kernel(
    const float* __restrict__ W0, const float* __restrict__ wmask,
    const int* __restrict__ ip, unsigned short* __restrict__ w0p) {
    size_t t = (size_t)blockIdx.x * 256 + threadIdx.x;
    size_t e = t * 8;
    int j = (int)(e >> 18);               // H*K = 262144 elems per j
    int k = (int)(e & (K_ - 1));          // [j][h][k] layout -> e % K
    const float* wi = wmask + ((size_t)ip[0] * J_ + j) * K_ + k;
    f32x4 s0 = *(const f32x4*)wi;
    f32x4 s1 = *(const f32x4*)(wi + 4);
    f32x4 a0 = *(const f32x4*)(W0 + e);
    f32x4 a1 = *(const f32x4*)(W0 + e + 4);
    a0 *= s0; a1 *= s1;
    u16x8 o;
    #pragma unroll
    for (int q = 0; q < 4; ++q) { o[q] = f2bf(a0[q]); o[q + 4] = f2bf(a1[q]); }
    *(u16x8*)(w0p + e) = o;
}

// Fast path GEMM: both operands bf16, staged via global_load_lds with
// pre-swizzled global source (LDS dest linear; read side applies same XOR).
// Block (j, mb, nb): 8192 blocks x 256 thr (4 waves), tile 128x128, BK=64.
__global__ __launch_bounds__(256, 3) void enc_kernel(
    const unsigned short* __restrict__ xbf,
    const unsigned short* __restrict__ w0p,
    const float* __restrict__ b0,
    const float* __restrict__ W1,
    float* __restrict__ out) {
    __shared__ unsigned char ldsA[128 * 128];
    __shared__ unsigned char ldsB[128 * 128];

    int p = blockIdx.x;
    int xcd = p & 7;
    int q = p >> 3;
    int j = (xcd << 5) + (q >> 5);
    int inner = q & 31;
    int m0 = (inner >> 2) << 7;
    int h0 = (inner & 3) << 7;

    int tid = threadIdx.x;
    int lane = tid & 63;
    int wv = tid >> 6;
    int wm = wv >> 1, wn = wv & 1;
    int lr = lane & 15, lg = lane >> 4;
    int lrow = lane >> 3;      // 0..7 within 8-row group
    int lch = lane & 7;        // 16B chunk
    int sch = ((lch ^ lrow) << 3);  // pre-swizzled source chunk (elems)

    // per-lane global bases (row = wv*32 + lrow), wave-uniform LDS bases
    const unsigned short* aBase = xbf + (size_t)(m0 + wv * 32 + lrow) * K_ + sch;
    const unsigned short* bBase = w0p + ((size_t)j * H_ + h0 + wv * 32 + lrow) * K_ + sch;
    unsigned char* laBase = ldsA + wv * 4096;
    unsigned char* lbBase = ldsB + wv * 4096;

    f32x4 acc[4][4] = {};

    for (int ks = 0; ks < K_ / BK; ++ks) {
        int k0 = ks * BK;
        #pragma unroll
        for (int ii = 0; ii < 4; ++ii) {
            gload_lds16(aBase + (size_t)ii * 8 * K_ + k0, laBase + ii * 1024);
            gload_lds16(bBase + (size_t)ii * 8 * K_ + k0, lbBase + ii * 1024);
        }
        __syncthreads();   // drains vmcnt + lgkm (m97 structure)
        #pragma unroll
        for (int kf = 0; kf < 2; ++kf) {
            bf16x8 af[4], bfr[4];
            #pragma unroll
            for (int mf = 0; mf < 4; ++mf) {
                int r = (wm << 6) + (mf << 4) + lr;
                af[mf] = *(const bf16x8*)(ldsA + r * 128 +
                          (((kf << 6) + (lg << 4)) ^ ((r & 7) << 4)));
            }
            #pragma unroll
            for (int nf = 0; nf < 4; ++nf) {
                int hrw = (wn << 6) + (nf << 4) + lr;
                bfr[nf] = *(const bf16x8*)(ldsB + hrw * 128 +
                          (((kf << 6) + (lg << 4)) ^ ((hrw & 7) << 4)));
            }
            #pragma unroll
            for (int mf = 0; mf < 4; ++mf)
                #pragma unroll
                for (int nf = 0; nf < 4; ++nf)
                    acc[mf][nf] = __builtin_amdgcn_mfma_f32_16x16x32_bf16(
                        af[mf], bfr[nf], acc[mf][nf], 0, 0, 0);
        }
        __syncthreads();
    }

    float b0v[4], w1v[4];
    #pragma unroll
    for (int nf = 0; nf < 4; ++nf) {
        int h = h0 + (wn << 6) + (nf << 4) + lr;
        b0v[nf] = b0[(size_t)j * H_ + h];
        w1v[nf] = W1[(size_t)j * H_ + h];
    }
    #pragma unroll
    for (int mf = 0; mf < 4; ++mf) {
        #pragma unroll
        for (int rg = 0; rg < 4; ++rg) {
            float ps = 0.f;
            #pragma unroll
            for (int nf = 0; nf < 4; ++nf) {
                float hv = acc[mf][nf][rg] + b0v[nf];
                hv = hv > 0.f ? hv : 0.01f * hv;
                ps += hv * w1v[nf];
            }
            ps += __shfl_xor(ps, 1);
            ps += __shfl_xor(ps, 2);
            ps += __shfl_xor(ps, 4);
            ps += __shfl_xor(ps, 8);
            if (lr == 0) {
                int row = m0 + (wm << 6) + (mf << 4) + (lg << 2) + rg;
                atomicAdd(out + (size_t)row * J_ + j, ps);
            }
        }
    }
}

// Fallback (ws too small): round-2 kernel — on-the-fly mask*W0 cvt staging.
__global__ __launch_bounds__(256, 2) void enc_kernel_fb(
    const unsigned short* __restrict__ xbf,
    const float* __restrict__ W0,
    const float* __restrict__ wmask,
    const int* __restrict__ ip,
    const float* __restrict__ b0,
    const float* __restrict__ W1,
    float* __restrict__ out) {
    __shared__ unsigned char ldsA[128 * 128];
    __shared__ unsigned char ldsB[128 * 128];

    int p = blockIdx.x;
    int xcd = p & 7;
    int q = p >> 3;
    int j = (xcd << 5) + (q >> 5);
    int inner = q & 31;
    int m0 = (inner >> 2) << 7;
    int h0 = (inner & 3) << 7;

    int i = ip[0];
    const float* w0j = W0 + (size_t)j * (H_ * K_);
    const float* wij = wmask + ((size_t)i * J_ + j) * K_;

    int tid = threadIdx.x;
    int lane = tid & 63;
    int wv = tid >> 6;
    int wm = wv >> 1, wn = wv & 1;
    int lr = lane & 15, lg = lane >> 4;
    int srow0 = tid >> 3;
    int c = tid & 7;

    f32x4 acc[4][4] = {};

    for (int ks = 0; ks < K_ / BK; ++ks) {
        int k0 = ks * BK;
        #pragma unroll
        for (int it = 0; it < 4; ++it) {
            int r = srow0 + it * 32;
            u32x4 v = *(const u32x4*)(xbf + (size_t)(m0 + r) * K_ + k0 + c * 8);
            *(u32x4*)(ldsA + r * 128 + ((c * 16) ^ ((r & 7) << 4))) = v;
        }
        f32x4 s0 = *(const f32x4*)(wij + k0 + c * 8);
        f32x4 s1 = *(const f32x4*)(wij + k0 + c * 8 + 4);
        #pragma unroll
        for (int it = 0; it < 4; ++it) {
            int hr = srow0 + it * 32;
            const float* src = w0j + (size_t)(h0 + hr) * K_ + k0 + c * 8;
            f32x4 a0 = *(const f32x4*)(src);
            f32x4 a1 = *(const f32x4*)(src + 4);
            a0 *= s0; a1 *= s1;
            u16x8 bv;
            #pragma unroll
            for (int e = 0; e < 4; ++e) { bv[e] = f2bf(a0[e]); bv[e + 4] = f2bf(a1[e]); }
            *(u16x8*)(ldsB + hr * 128 + ((c * 16) ^ ((hr & 7) << 4))) = bv;
        }
        __syncthreads();
        #pragma unroll
        for (int kf = 0; kf < 2; ++kf) {
            bf16x8 af[4], bfr[4];
            #pragma unroll
            for (int mf = 0; mf < 4; ++mf) {
                int r = (wm << 6) + (mf << 4) + lr;
                af[mf] = *(const bf16x8*)(ldsA + r * 128 +
                          (((kf << 6) + (lg << 4)) ^ ((r & 7) << 4)));
            }
            #pragma unroll
            for (int nf = 0; nf < 4; ++nf) {
                int hrw = (wn << 6) + (nf << 4) + lr;
                bfr[nf] = *(const bf16x8*)(ldsB + hrw * 128 +
                          (((kf << 6) + (lg << 4)) ^ ((hrw & 7) << 4)));
            }
            #pragma unroll
            for (int mf = 0; mf < 4; ++mf)
                #pragma unroll
                for (int nf = 0; nf < 4; ++nf)
                    acc[mf][nf] = __builtin_amdgcn_mfma_f32_16x16x32_bf16(
                        af[mf], bfr[nf], acc[mf][nf], 0, 0, 0);
        }
        __syncthreads();
    }

    float b0v[4], w1v[4];
    #pragma unroll
    for (int nf = 0; nf < 4; ++nf) {
        int h = h0 + (wn << 6) + (nf << 4) + lr;
        b0v[nf] = b0[(size_t)j * H_ + h];
        w1v[nf] = W1[(size_t)j * H_ + h];
    }
    #pragma unroll
    for (int mf = 0; mf < 4; ++mf) {
        #pragma unroll
        for (int rg = 0; rg < 4; ++rg) {
            float ps = 0.f;
            #pragma unroll
            for (int nf = 0; nf < 4; ++nf) {
                float hv = acc[mf][nf][rg] + b0v[nf];
                hv = hv > 0.f ? hv : 0.01f * hv;
                ps += hv * w1v[nf];
            }
            ps += __shfl_xor(ps, 1);
            ps += __shfl_xor(ps, 2);
            ps += __shfl_xor(ps, 4);
            ps += __shfl_xor(ps, 8);
            if (lr == 0) {
                int row = m0 + (wm << 6) + (mf << 4) + (lg << 2) + rg;
                atomicAdd(out + (size_t)row * J_ + j, ps);
            }
        }
    }
}

extern "C" void kernel_launch(void* const* d_in, const int* in_sizes, int n_in,
                              void* d_out, int out_size, void* d_ws, size_t ws_size,
                              hipStream_t stream) {
    const float* x      = (const float*)d_in[0];
    const int*   ip     = (const int*)d_in[1];
    const float* wmask  = (const float*)d_in[2];
    const float* W0     = (const float*)d_in[3];
    const float* b0     = (const float*)d_in[4];
    const float* W1     = (const float*)d_in[5];
    const float* b1     = (const float*)d_in[6];
    const float* logvar = (const float*)d_in[7];
    float* out = (float*)d_out;
    unsigned short* xbf = (unsigned short*)d_ws;          // 1 MB
    const size_t xbf_elems = (size_t)B_ * K_;
    const size_t w0p_bytes = (size_t)J_ * H_ * K_ * 2;    // 134.2 MB
    const size_t need = xbf_elems * 2 + w0p_bytes;

    prep_kernel<<<512, 256, 0, stream>>>(x, b1, logvar, xbf, out);
    if (ws_size >= need) {
        unsigned short* w0p = xbf + xbf_elems;
        wprep_kernel<<<32768, 256, 0, stream>>>(W0, wmask, ip, w0p);
        enc_kernel<<<8192, 256, 0, stream>>>(xbf, w0p, b0, W1, out);
    } else {
        enc_kernel_fb<<<8192, 256, 0, stream>>>(xbf, W0, wmask, ip, b0, W1, out);
    }
}

// Round 4
// 573.065 us; speedup vs baseline: 1.0172x; 1.0163x over previous
//
#include <hip/hip_runtime.h>

// Problem constants (from reference): D=4, J=256, K=512, H=512, B=1024
#define J_ 256
#define K_ 512
#define H_ 512
#define B_ 1024
#define BK 64

typedef float f32x4 __attribute__((ext_vector_type(4)));
typedef unsigned short u16x4 __attribute__((ext_vector_type(4)));
typedef unsigned short u16x8 __attribute__((ext_vector_type(8)));
typedef __bf16 bf16x8 __attribute__((ext_vector_type(8)));

// f32 -> bf16 round-to-nearest-even (manual; inputs are finite)
__device__ __forceinline__ unsigned short f2bf(float f) {
    unsigned int u = __float_as_uint(f);
    u += 0x7fffu + ((u >> 16) & 1u);
    return (unsigned short)(u >> 16);
}

// async global->LDS, 16B per lane; LDS dest is wave-uniform base + lane*16
__device__ __forceinline__ void gload_lds16(const void* g, void* l) {
    __builtin_amdgcn_global_load_lds(
        (const __attribute__((address_space(1))) unsigned int*)g,
        (__attribute__((address_space(3))) unsigned int*)l, 16, 0, 0);
}

// Prep: x f32 -> bf16 into ws; init out: mu[b,j] = b1[j]; logvar tail.
__global__ __launch_bounds__(256) void prep_kernel(
    const float* __restrict__ x, const float* __restrict__ b1,
    const float* __restrict__ logvar, unsigned short* __restrict__ xbf,
    float* __restrict__ out) {
    int t = blockIdx.x * 256 + threadIdx.x;
    {
        f32x4 v = *(const f32x4*)(x + (size_t)t * 4);
        u16x4 o;
        o[0] = f2bf(v[0]); o[1] = f2bf(v[1]); o[2] = f2bf(v[2]); o[3] = f2bf(v[3]);
        *(u16x4*)(xbf + (size_t)t * 4) = o;
    }
    if (t < (B_ * J_) / 4) {
        int b = t >> 6;
        int j4 = (t & 63) << 2;
        f32x4 bb = *(const f32x4*)(b1 + j4);
        *(f32x4*)(out + ((size_t)b << 8) + j4) = bb;
    }
    if (t < 4) out[B_ * J_ + t] = logvar[t];
}

// Grouped GEMM with LDS-resident, in-kernel-converted W0' panel.
// Grid: 2048 blocks = (j 0..255) x (hb 0..7); 256 threads = 4 waves.
// Block: converts W0[j, hb*64:(hb+1)*64, :]*wi -> ldsB (64 KB bf16, full K)
// exactly once, then 8 m-tiles x 8 K-steps; x tile (128x64) staged per step
// via global_load_lds with pre-swizzled source. LDS 80 KB -> 2 blocks/CU.
__global__ __launch_bounds__(256, 2) void enc_kernel(
    const unsigned short* __restrict__ xbf,
    const float* __restrict__ W0,
    const float* __restrict__ wmask,
    const int* __restrict__ ip,
    const float* __restrict__ b0,
    const float* __restrict__ W1,
    float* __restrict__ out) {
    __shared__ unsigned char ldsB[64 * 1024];   // 64 h-rows x 512 k bf16, XOR-swizzled
    __shared__ unsigned char ldsX[128 * 128];   // 128 m-rows x 64 k bf16, XOR-swizzled

    int p = blockIdx.x;
    int j = p >> 3;
    int hb = p & 7;
    int h0 = hb << 6;

    int tid = threadIdx.x;
    int lane = tid & 63;
    int wv = tid >> 6;
    int lr = lane & 15, lg = lane >> 4;

    // ---- phase 0: convert W0'[j, h0:h0+64, :] into ldsB (once per block) ----
    {
        const float* w0p = W0 + ((size_t)j * H_ + h0) * K_;
        const float* wij = wmask + ((size_t)ip[0] * J_ + j) * K_;
        int row = (wv << 4) + lr;           // 0..63, each exactly once per cb
        int cb = lg;                        // 0..3 chunk phase
        const float* src = w0p + (size_t)row * K_;
        unsigned int swb = ((unsigned)row & 7u) << 4;
        unsigned char* dst = ldsB + row * 1024;
        #pragma unroll
        for (int qq = 0; qq < 16; ++qq) {
            int c = cb + (qq << 2);         // 16B chunk index 0..63
            int k = c << 3;
            f32x4 a0 = *(const f32x4*)(src + k);
            f32x4 a1 = *(const f32x4*)(src + k + 4);
            f32x4 s0 = *(const f32x4*)(wij + k);
            f32x4 s1 = *(const f32x4*)(wij + k + 4);
            a0 *= s0; a1 *= s1;
            u16x8 o;
            #pragma unroll
            for (int e = 0; e < 4; ++e) { o[e] = f2bf(a0[e]); o[e + 4] = f2bf(a1[e]); }
            *(u16x8*)(dst + (((unsigned)c << 4) ^ swb)) = o;
        }
    }

    // x staging coords: wave wv stages rows [wv*32, wv*32+32) of the 128-row tile
    int lrow = lane >> 3;                   // 0..7
    int lch = lane & 7;
    int sch = ((lch ^ lrow) << 3);          // pre-swizzled source chunk (elems)
    const unsigned short* aBase = xbf + (size_t)(wv * 32 + lrow) * K_ + sch;
    unsigned char* laBase = ldsX + wv * 4096;

    // epilogue constants
    float b0v[4], w1v[4];
    #pragma unroll
    for (int nf = 0; nf < 4; ++nf) {
        int col = h0 + (nf << 4) + lr;
        b0v[nf] = b0[(size_t)j * H_ + col];
        w1v[nf] = W1[(size_t)j * H_ + col];
    }

    __syncthreads();                        // ldsB panel ready

    for (int mt = 0; mt < 8; ++mt) {
        int m0 = mt << 7;
        f32x4 acc[2][4] = {};               // wave tile 32(m) x 64(h)
        for (int ks = 0; ks < 8; ++ks) {
            int k0 = ks * BK;
            #pragma unroll
            for (int ii = 0; ii < 4; ++ii)
                gload_lds16(aBase + (size_t)(m0 + ii * 8) * K_ + k0, laBase + ii * 1024);
            __syncthreads();
            #pragma unroll
            for (int kf = 0; kf < 2; ++kf) {
                bf16x8 af[2], bfv[4];
                #pragma unroll
                for (int mf = 0; mf < 2; ++mf) {
                    int r = (wv << 5) + (mf << 4) + lr;
                    af[mf] = *(const bf16x8*)(ldsX + r * 128 +
                              (((kf << 6) + (lg << 4)) ^ ((r & 7) << 4)));
                }
                #pragma unroll
                for (int nf = 0; nf < 4; ++nf) {
                    int row = (nf << 4) + lr;
                    bfv[nf] = *(const bf16x8*)(ldsB + row * 1024 +
                              (((ks << 7) + (kf << 6) + (lg << 4)) ^ ((row & 7) << 4)));
                }
                #pragma unroll
                for (int mf = 0; mf < 2; ++mf)
                    #pragma unroll
                    for (int nf = 0; nf < 4; ++nf)
                        acc[mf][nf] = __builtin_amdgcn_mfma_f32_16x16x32_bf16(
                            af[mf], bfv[nf], acc[mf][nf], 0, 0, 0);
            }
            __syncthreads();
        }
        // fused epilogue for this m-tile: h = leaky(acc + b0); partial mu = h . W1
        #pragma unroll
        for (int mf = 0; mf < 2; ++mf) {
            #pragma unroll
            for (int rg = 0; rg < 4; ++rg) {
                float ps = 0.f;
                #pragma unroll
                for (int nf = 0; nf < 4; ++nf) {
                    float hv = acc[mf][nf][rg] + b0v[nf];  // C/D: col=lr, row=lg*4+rg
                    hv = hv > 0.f ? hv : 0.01f * hv;
                    ps += hv * w1v[nf];
                }
                ps += __shfl_xor(ps, 1);
                ps += __shfl_xor(ps, 2);
                ps += __shfl_xor(ps, 4);
                ps += __shfl_xor(ps, 8);
                if (lr == 0) {
                    int row = m0 + (wv << 5) + (mf << 4) + (lg << 2) + rg;
                    atomicAdd(out + (size_t)row * J_ + j, ps);
                }
            }
        }
    }
}

extern "C" void kernel_launch(void* const* d_in, const int* in_sizes, int n_in,
                              void* d_out, int out_size, void* d_ws, size_t ws_size,
                              hipStream_t stream) {
    const float* x      = (const float*)d_in[0];
    const int*   ip     = (const int*)d_in[1];
    const float* wmask  = (const float*)d_in[2];
    const float* W0     = (const float*)d_in[3];
    const float* b0     = (const float*)d_in[4];
    const float* W1     = (const float*)d_in[5];
    const float* b1     = (const float*)d_in[6];
    const float* logvar = (const float*)d_in[7];
    float* out = (float*)d_out;
    unsigned short* xbf = (unsigned short*)d_ws;   // 1 MB

    prep_kernel<<<512, 256, 0, stream>>>(x, b1, logvar, xbf, out);
    enc_kernel<<<2048, 256, 0, stream>>>(xbf, W0, wmask, ip, b0, W1, out);
}